// Round 3
// baseline (5902.827 us; speedup 1.0000x reference)
//
#include <hip/hip_runtime.h>
#include <hip/hip_fp16.h>

#define B_SZ 64
#define T_SZ 2048
#define D_SZ 256
#define H_SZ 256
#define G3   768
#define M_SZ (B_SZ * T_SZ) // 131072

typedef _Float16 half2v __attribute__((ext_vector_type(2)));
typedef _Float16 half4v __attribute__((ext_vector_type(4)));
typedef _Float16 half8v __attribute__((ext_vector_type(8)));
typedef float    f32x4  __attribute__((ext_vector_type(4)));

static __device__ __forceinline__ float fdot2f(uint a, uint b, float acc) {
#if __has_builtin(__builtin_amdgcn_fdot2)
  return __builtin_amdgcn_fdot2(__builtin_bit_cast(half2v, a),
                                __builtin_bit_cast(half2v, b), acc, false);
#else
  half2v av = __builtin_bit_cast(half2v, a), bv = __builtin_bit_cast(half2v, b);
  acc = fmaf((float)av[0], (float)bv[0], acc);
  acc = fmaf((float)av[1], (float)bv[1], acc);
  return acc;
#endif
}

static __device__ __forceinline__ float h2f(ushort u) {
  return (float)__builtin_bit_cast(_Float16, u);
}
static __device__ __forceinline__ ushort f2h(float x) {
  return __builtin_bit_cast(ushort, (_Float16)x);
}
static __device__ __forceinline__ float fast_rcp(float x) {
  return __builtin_amdgcn_rcpf(x);
}

// ---------- prep 1: Wx f32 -> f16 (GEMM B operand) ----------
__global__ void prep_wx(const float* __restrict__ Wx, ushort* __restrict__ Wxh) {
  int i = blockIdx.x * 256 + threadIdx.x;
  if (i < G3 * D_SZ) Wxh[i] = f2h(Wx[i]);
}

// ---------- prep 2: Wh -> packed transposed f16 pairs ----------
// Wp[kp*768 + j] = (f16(Wh[j][2kp]), f16(Wh[j][2kp+1]))  for kp in [0,128), j in [0,768)
__global__ void prep_wh(const float* __restrict__ Wh, uint* __restrict__ Wp) {
  int j = blockIdx.x * 256 + threadIdx.x; // 0..767
  int kp = blockIdx.y;                    // 0..127
  float a = Wh[(size_t)j * D_SZ + 2 * kp];
  float b = Wh[(size_t)j * D_SZ + 2 * kp + 1];
  uint lo = (uint)f2h(a), hi = (uint)f2h(b);
  Wp[(size_t)kp * G3 + j] = lo | (hi << 16);
}

// ---------- GEMM: xs[m, g] = inputs[m, :] . Wx[g, :] + bx[g], stored f16 ----------
// BM=128, BN=256, K=256 (BK=64 x 4). 256 threads = 4 waves (2x2), wave tile 64x128.
__global__ __launch_bounds__(256) void gemm_x(
    const float* __restrict__ A,   // [M_SZ, 256] f32
    const ushort* __restrict__ Bw, // Wx f16 [768, 256]
    const float* __restrict__ bx,  // [768] f32
    ushort* __restrict__ xs) {     // [M_SZ, 768] f16
  __shared__ _Float16 As[128][72];
  __shared__ _Float16 Bs[256][72];
  const int nt = blockIdx.x, mt = blockIdx.y;
  const int tid = threadIdx.x;
  const int lane = tid & 63, wv = tid >> 6;
  const int wr = (wv >> 1) * 64, wc = (wv & 1) * 128;
  const int l15 = lane & 15, l4 = lane >> 4;
  f32x4 acc[4][8] = {};
  for (int kt = 0; kt < 4; kt++) {
#pragma unroll
    for (int i = 0; i < 8; i++) {
      int f = tid + i * 256;
      int r = f >> 4, c4 = f & 15;
      float4 v = *(const float4*)(A + (size_t)(mt * 128 + r) * D_SZ + kt * 64 + c4 * 4);
      half4v h;
      h[0] = (_Float16)v.x; h[1] = (_Float16)v.y;
      h[2] = (_Float16)v.z; h[3] = (_Float16)v.w;
      *(half4v*)&As[r][c4 * 4] = h;
    }
#pragma unroll
    for (int i = 0; i < 8; i++) {
      int f = tid + i * 256;
      int r = f >> 3, c8 = f & 7;
      uint4 v = *(const uint4*)(Bw + (size_t)(nt * 256 + r) * D_SZ + kt * 64 + c8 * 8);
      *(uint4*)&Bs[r][c8 * 8] = v;
    }
    __syncthreads();
#pragma unroll
    for (int kk = 0; kk < 2; kk++) {
      half8v af[4], bf[8];
#pragma unroll
      for (int m = 0; m < 4; m++)
        af[m] = *(const half8v*)&As[wr + m * 16 + l15][kk * 32 + l4 * 8];
#pragma unroll
      for (int n = 0; n < 8; n++)
        bf[n] = *(const half8v*)&Bs[wc + n * 16 + l15][kk * 32 + l4 * 8];
#pragma unroll
      for (int m = 0; m < 4; m++) {
#pragma unroll
        for (int n = 0; n < 8; n++) {
          acc[m][n] = __builtin_amdgcn_mfma_f32_16x16x32_f16(af[m], bf[n], acc[m][n], 0, 0, 0);
        }
      }
    }
    __syncthreads();
  }
#pragma unroll
  for (int n = 0; n < 8; n++) {
    int col = nt * 256 + wc + n * 16 + l15;
    float bxv = bx[col];
#pragma unroll
    for (int m = 0; m < 4; m++) {
#pragma unroll
      for (int v4 = 0; v4 < 4; v4++) {
        int row = mt * 128 + wr + m * 16 + l4 * 4 + v4;
        xs[(size_t)row * G3 + col] = f2h(acc[m][n][v4] + bxv);
      }
    }
  }
}

// ---------- recurrence: one WG of 256 threads per batch (4 waves, 1/SIMD) ----------
// Thread i owns hidden unit i: all 3 gate rows (r,u,n) = 384 uint f16-pair regs.
// h lives in double-buffered LDS (f16), broadcast-read by all threads.
// One barrier per step (raw s_barrier + lgkmcnt-only wait: no vmcnt(0) drain,
// so the out-store and next-x loads stay in flight across the barrier).
__global__ __launch_bounds__(256, 1) void gru_rec(
    const ushort* __restrict__ xs, // [B, T, 768] f16
    const uint* __restrict__ Wp,   // [128][768] f16-pairs, transposed Wh
    const float* __restrict__ bh,  // [768]
    const float* __restrict__ hid, // [1, B, 256]
    float* __restrict__ out) {     // [B, T, 256] f32
  const int b = blockIdx.x;
  const int i = threadIdx.x;
  __shared__ alignas(16) ushort hbuf[2][H_SZ];

  // load weights: coalesced dword loads from the packed transposed layout
  uint wr[128], wu[128], wn[128];
#pragma unroll
  for (int kp = 0; kp < 128; kp++) {
    wr[kp] = Wp[(size_t)kp * G3 + i];
    wu[kp] = Wp[(size_t)kp * G3 + 256 + i];
    wn[kp] = Wp[(size_t)kp * G3 + 512 + i];
  }
  const float bhr = bh[i], bhu = bh[256 + i], bhn = bh[512 + i];

  float hprev = hid[b * H_SZ + i];
  hbuf[0][i] = f2h(hprev);
  __syncthreads();

  const ushort* xrow = xs + (size_t)b * T_SZ * G3 + i;
  float* orow = out + (size_t)b * T_SZ * H_SZ + i;

#pragma unroll 1
  for (int t = 0; t < T_SZ; t++) {
    // x pre-activations for this step (latency hidden under the dot chain)
    ushort xr16 = xrow[0];
    ushort xu16 = xrow[256];
    ushort xn16 = xrow[512];
    xrow += G3;

    // Wh[{r,u,n} row i] . h : 384 dot2 in 6 chains
    float ar0 = 0.f, ar1 = 0.f, au0 = 0.f, au1 = 0.f, an0 = 0.f, an1 = 0.f;
    const uint4* hq = (const uint4*)hbuf[t & 1];
#pragma unroll
    for (int c = 0; c < 32; c++) {
      uint4 q = hq[c];
      ar0 = fdot2f(wr[4 * c + 0], q.x, ar0);
      ar1 = fdot2f(wr[4 * c + 1], q.y, ar1);
      au0 = fdot2f(wu[4 * c + 0], q.x, au0);
      au1 = fdot2f(wu[4 * c + 1], q.y, au1);
      an0 = fdot2f(wn[4 * c + 0], q.x, an0);
      an1 = fdot2f(wn[4 * c + 1], q.y, an1);
      ar0 = fdot2f(wr[4 * c + 2], q.z, ar0);
      ar1 = fdot2f(wr[4 * c + 3], q.w, ar1);
      au0 = fdot2f(wu[4 * c + 2], q.z, au0);
      au1 = fdot2f(wu[4 * c + 3], q.w, au1);
      an0 = fdot2f(wn[4 * c + 2], q.z, an0);
      an1 = fdot2f(wn[4 * c + 3], q.w, an1);
    }
    float pre_r = ar0 + ar1 + bhr;
    float pre_u = au0 + au1 + bhu;
    float pre_n = an0 + an1 + bhn;

    float r = fast_rcp(1.f + __expf(-(h2f(xr16) + pre_r)));
    float u = fast_rcp(1.f + __expf(-(h2f(xu16) + pre_u)));
    float arg = h2f(xn16) + r * pre_n;
    float e = __expf(-2.f * fabsf(arg));
    float th = copysignf((1.f - e) * fast_rcp(1.f + e), arg);
    float hn = u * hprev + (1.f - u) * th;

    orow[(size_t)t * H_SZ] = hn;      // fire-and-forget (no vmcnt drain below)
    hbuf[(t + 1) & 1][i] = f2h(hn);
    hprev = hn;

    // LDS-only fence + raw barrier: h writes visible, stores stay in flight
    asm volatile("s_waitcnt lgkmcnt(0)" ::: "memory");
    __builtin_amdgcn_s_barrier();
  }
}

extern "C" void kernel_launch(void* const* d_in, const int* in_sizes, int n_in,
                              void* d_out, int out_size, void* d_ws, size_t ws_size,
                              hipStream_t stream) {
  const float* inp = (const float*)d_in[0]; // [B,T,D] f32
  const float* hid = (const float*)d_in[1]; // [1,B,H] f32
  const float* Wx  = (const float*)d_in[2]; // [768,256] f32
  const float* bx  = (const float*)d_in[3]; // [768] f32
  const float* Wh  = (const float*)d_in[4]; // [768,256] f32
  const float* bh  = (const float*)d_in[5]; // [768] f32
  float* out = (float*)d_out;

  // workspace: xs f16 [M_SZ,768] (192 MiB), Wxh f16 (384 KiB), Wp uint (384 KiB)
  char* ws = (char*)d_ws;
  ushort* xs = (ushort*)ws;
  size_t xs_bytes = (size_t)M_SZ * G3 * sizeof(ushort);
  ushort* Wxh = (ushort*)(ws + xs_bytes);
  uint* Wp = (uint*)(ws + xs_bytes + (size_t)G3 * D_SZ * sizeof(ushort));

  prep_wx<<<768, 256, 0, stream>>>(Wx, Wxh);
  prep_wh<<<dim3(3, 128), 256, 0, stream>>>(Wh, Wp);
  gemm_x<<<dim3(3, 1024), 256, 0, stream>>>(inp, Wxh, bx, xs);
  gru_rec<<<B_SZ, 256, 0, stream>>>(xs, Wp, bh, hid, out);
}

// Round 4
// 2937.728 us; speedup vs baseline: 2.0093x; 2.0093x over previous
//
#include <hip/hip_runtime.h>
#include <hip/hip_fp16.h>

#define B_SZ 64
#define T_SZ 2048
#define D_SZ 256
#define H_SZ 256
#define G3   768
#define M_SZ (B_SZ * T_SZ) // 131072

typedef _Float16 half2v __attribute__((ext_vector_type(2)));
typedef _Float16 half4v __attribute__((ext_vector_type(4)));
typedef _Float16 half8v __attribute__((ext_vector_type(8)));
typedef float    f32x4  __attribute__((ext_vector_type(4)));

static __device__ __forceinline__ float fdot2f(uint a, uint b, float acc) {
#if __has_builtin(__builtin_amdgcn_fdot2)
  return __builtin_amdgcn_fdot2(__builtin_bit_cast(half2v, a),
                                __builtin_bit_cast(half2v, b), acc, false);
#else
  half2v av = __builtin_bit_cast(half2v, a), bv = __builtin_bit_cast(half2v, b);
  acc = fmaf((float)av[0], (float)bv[0], acc);
  acc = fmaf((float)av[1], (float)bv[1], acc);
  return acc;
#endif
}

static __device__ __forceinline__ float h2f(ushort u) {
  return (float)__builtin_bit_cast(_Float16, u);
}
static __device__ __forceinline__ ushort f2h(float x) {
  return __builtin_bit_cast(ushort, (_Float16)x);
}
static __device__ __forceinline__ float fast_rcp(float x) {
  return __builtin_amdgcn_rcpf(x);
}

// ---------- prep 1: Wx f32 -> f16 (GEMM B operand) ----------
__global__ void prep_wx(const float* __restrict__ Wx, ushort* __restrict__ Wxh) {
  int i = blockIdx.x * 256 + threadIdx.x;
  if (i < G3 * D_SZ) Wxh[i] = f2h(Wx[i]);
}

// ---------- prep 2: Wh -> per-thread packed f16-pair slots for gru_rec ----------
// Thread layout in gru_rec (512 threads):
//   tid<256 (i=tid):    s in [0,128): row=i      kp=s       (gate r, full row)
//                       s in [128,192): row=512+i kp=s-128  (gate n, k-lo half)
//   tid>=256 (i=tid-256): s in [0,128): row=256+i kp=s      (gate u, full row)
//                       s in [128,192): row=512+i kp=64+(s-128) (gate n, k-hi half)
// Storage (for coalesced dwordx4): dword index = ((s>>2)*512 + tid)*4 + (s&3)
__global__ void prep_wq(const float* __restrict__ Wh, uint* __restrict__ Wq) {
  int idx = blockIdx.x * 256 + threadIdx.x; // 0 .. 192*512-1
  int s = idx >> 9;
  int tid = idx & 511;
  int row, kp;
  if (tid < 256) {
    if (s < 128) { row = tid;        kp = s; }
    else         { row = 512 + tid;  kp = s - 128; }
  } else {
    int i = tid - 256;
    if (s < 128) { row = 256 + i;    kp = s; }
    else         { row = 512 + i;    kp = 64 + (s - 128); }
  }
  float a = Wh[(size_t)row * D_SZ + 2 * kp];
  float b = Wh[(size_t)row * D_SZ + 2 * kp + 1];
  uint lo = (uint)f2h(a), hi = (uint)f2h(b);
  Wq[((size_t)(s >> 2) * 512 + tid) * 4 + (s & 3)] = lo | (hi << 16);
}

// ---------- GEMM: xs[m, g] = inputs[m, :] . Wx[g, :] + bx[g], stored f16 ----------
__global__ __launch_bounds__(256) void gemm_x(
    const float* __restrict__ A,   // [M_SZ, 256] f32
    const ushort* __restrict__ Bw, // Wx f16 [768, 256]
    const float* __restrict__ bx,  // [768] f32
    ushort* __restrict__ xs) {     // [M_SZ, 768] f16
  __shared__ _Float16 As[128][72];
  __shared__ _Float16 Bs[256][72];
  const int nt = blockIdx.x, mt = blockIdx.y;
  const int tid = threadIdx.x;
  const int lane = tid & 63, wv = tid >> 6;
  const int wr = (wv >> 1) * 64, wc = (wv & 1) * 128;
  const int l15 = lane & 15, l4 = lane >> 4;
  f32x4 acc[4][8] = {};
  for (int kt = 0; kt < 4; kt++) {
#pragma unroll
    for (int i = 0; i < 8; i++) {
      int f = tid + i * 256;
      int r = f >> 4, c4 = f & 15;
      float4 v = *(const float4*)(A + (size_t)(mt * 128 + r) * D_SZ + kt * 64 + c4 * 4);
      half4v h;
      h[0] = (_Float16)v.x; h[1] = (_Float16)v.y;
      h[2] = (_Float16)v.z; h[3] = (_Float16)v.w;
      *(half4v*)&As[r][c4 * 4] = h;
    }
#pragma unroll
    for (int i = 0; i < 8; i++) {
      int f = tid + i * 256;
      int r = f >> 3, c8 = f & 7;
      uint4 v = *(const uint4*)(Bw + (size_t)(nt * 256 + r) * D_SZ + kt * 64 + c8 * 8);
      *(uint4*)&Bs[r][c8 * 8] = v;
    }
    __syncthreads();
#pragma unroll
    for (int kk = 0; kk < 2; kk++) {
      half8v af[4], bf[8];
#pragma unroll
      for (int m = 0; m < 4; m++)
        af[m] = *(const half8v*)&As[wr + m * 16 + l15][kk * 32 + l4 * 8];
#pragma unroll
      for (int n = 0; n < 8; n++)
        bf[n] = *(const half8v*)&Bs[wc + n * 16 + l15][kk * 32 + l4 * 8];
#pragma unroll
      for (int m = 0; m < 4; m++) {
#pragma unroll
        for (int n = 0; n < 8; n++) {
          acc[m][n] = __builtin_amdgcn_mfma_f32_16x16x32_f16(af[m], bf[n], acc[m][n], 0, 0, 0);
        }
      }
    }
    __syncthreads();
  }
#pragma unroll
  for (int n = 0; n < 8; n++) {
    int col = nt * 256 + wc + n * 16 + l15;
    float bxv = bx[col];
#pragma unroll
    for (int m = 0; m < 4; m++) {
#pragma unroll
      for (int v4 = 0; v4 < 4; v4++) {
        int row = mt * 128 + wr + m * 16 + l4 * 4 + v4;
        xs[(size_t)row * G3 + col] = f2h(acc[m][n][v4] + bxv);
      }
    }
  }
}

// ---------- recurrence: 512 threads/block (8 waves, 2 waves/SIMD) ----------
// 192 weight dwords per thread (fits 256-VGPR budget at 2 waves/SIMD).
// tid<256: gate-r row i + n-row-lo; tid>=256: gate-u row i + n-row-hi.
// h double-buffered in LDS (f16 pairs, broadcast reads). 2 raw barriers/step
// with lgkmcnt-only waits (out-stores and x-loads stay in flight).
__global__ __launch_bounds__(512, 2) void gru_rec(
    const ushort* __restrict__ xs, // [B, T, 768] f16
    const uint* __restrict__ Wq,   // packed per-thread weights
    const float* __restrict__ bh,  // [768]
    const float* __restrict__ hid, // [1, B, 256]
    float* __restrict__ out) {     // [B, T, 256] f32
  const int b = blockIdx.x;
  const int tid = threadIdx.x;
  const int i = tid & 255;
  const int nbase4 = (tid < 256) ? 0 : 16; // which h-quarter the n-half uses

  __shared__ alignas(16) ushort hbuf[2][H_SZ];
  __shared__ float us[H_SZ];
  __shared__ float nh[H_SZ];

  // 48 coalesced dwordx4 weight loads -> 192 registers
  uint w[192];
  {
    const uint4* wp = (const uint4*)Wq + tid;
#pragma unroll
    for (int s4 = 0; s4 < 48; s4++) {
      uint4 v = wp[(size_t)s4 * 512];
      w[4 * s4 + 0] = v.x; w[4 * s4 + 1] = v.y;
      w[4 * s4 + 2] = v.z; w[4 * s4 + 3] = v.w;
    }
  }
  const float bh_pre = bh[tid];           // r-bias (tid<256) or u-bias (tid>=256)
  const float bh_n = bh[512 + i];
  float hprev = 0.f;
  if (tid < 256) {
    hprev = hid[b * H_SZ + tid];
    hbuf[0][tid] = f2h(hprev);
  }
  __syncthreads();

  const ushort* xrow = xs + (size_t)b * T_SZ * G3;
  float* orow = out + (size_t)b * T_SZ * H_SZ + i;

  // x prefetch (1-step ahead): xa = own-gate pre-act, xb = x_n (side1 unused)
  ushort xa_c = xrow[tid];
  ushort xb_c = xrow[512 + i];

#pragma unroll 1
  for (int t = 0; t < T_SZ; t++) {
    const ushort* xnxt = xrow + (t + 1 < T_SZ ? (size_t)(t + 1) * G3 : 0);
    ushort xa_n = xnxt[tid];
    ushort xb_n = xnxt[512 + i];

    // --- dots: 128 dot2 for the full gate row, 64 for the n-half ---
    float a0 = 0.f, a1 = 0.f, n0 = 0.f, n1 = 0.f;
    const uint4* hq = (const uint4*)hbuf[t & 1];
#pragma unroll
    for (int c = 0; c < 32; c++) {
      uint4 q = hq[c];
      a0 = fdot2f(w[4 * c + 0], q.x, a0);
      a1 = fdot2f(w[4 * c + 1], q.y, a1);
      a0 = fdot2f(w[4 * c + 2], q.z, a0);
      a1 = fdot2f(w[4 * c + 3], q.w, a1);
    }
#pragma unroll
    for (int c2 = 0; c2 < 16; c2++) {
      uint4 q = hq[nbase4 + c2];
      n0 = fdot2f(w[128 + 4 * c2 + 0], q.x, n0);
      n1 = fdot2f(w[128 + 4 * c2 + 1], q.y, n1);
      n0 = fdot2f(w[128 + 4 * c2 + 2], q.z, n0);
      n1 = fdot2f(w[128 + 4 * c2 + 3], q.w, n1);
    }
    float pre = a0 + a1 + bh_pre;
    float npart = n0 + n1;
    float sg = fast_rcp(1.f + __expf(-(h2f(xa_c) + pre))); // r (side0) / u (side1)

    if (tid >= 256) {
      us[i] = sg;
      nh[i] = npart;
    }
    asm volatile("s_waitcnt lgkmcnt(0)" ::: "memory");
    __builtin_amdgcn_s_barrier();

    if (tid < 256) {
      float u = us[i];
      float pre_n = npart + nh[i] + bh_n;
      float arg = h2f(xb_c) + sg * pre_n;
      float e = __expf(-2.f * fabsf(arg));
      float th = copysignf((1.f - e) * fast_rcp(1.f + e), arg);
      float hn = u * hprev + (1.f - u) * th;
      orow[(size_t)t * H_SZ] = hn;          // fire-and-forget
      hbuf[(t + 1) & 1][i] = f2h(hn);
      hprev = hn;
    }
    asm volatile("s_waitcnt lgkmcnt(0)" ::: "memory");
    __builtin_amdgcn_s_barrier();

    xa_c = xa_n;
    xb_c = xb_n;
  }
}

extern "C" void kernel_launch(void* const* d_in, const int* in_sizes, int n_in,
                              void* d_out, int out_size, void* d_ws, size_t ws_size,
                              hipStream_t stream) {
  const float* inp = (const float*)d_in[0]; // [B,T,D] f32
  const float* hid = (const float*)d_in[1]; // [1,B,H] f32
  const float* Wx  = (const float*)d_in[2]; // [768,256] f32
  const float* bx  = (const float*)d_in[3]; // [768] f32
  const float* Wh  = (const float*)d_in[4]; // [768,256] f32
  const float* bh  = (const float*)d_in[5]; // [768] f32
  float* out = (float*)d_out;

  // workspace: xs f16 [M_SZ,768] (192 MiB), Wxh f16 (384 KiB), Wq uint (384 KiB)
  char* ws = (char*)d_ws;
  ushort* xs = (ushort*)ws;
  size_t xs_bytes = (size_t)M_SZ * G3 * sizeof(ushort);
  ushort* Wxh = (ushort*)(ws + xs_bytes);
  uint* Wq = (uint*)(ws + xs_bytes + (size_t)G3 * D_SZ * sizeof(ushort));

  prep_wx<<<768, 256, 0, stream>>>(Wx, Wxh);
  prep_wq<<<384, 256, 0, stream>>>(Wh, Wq);
  gemm_x<<<dim3(3, 1024), 256, 0, stream>>>(inp, Wxh, bx, xs);
  gru_rec<<<B_SZ, 512, 0, stream>>>(xs, Wq, bh, hid, out);
}

// Round 5
// 2567.736 us; speedup vs baseline: 2.2988x; 1.1441x over previous
//
#include <hip/hip_runtime.h>
#include <hip/hip_fp16.h>

#define B_SZ 64
#define T_SZ 2048
#define D_SZ 256
#define H_SZ 256
#define G3   768
#define M_SZ (B_SZ * T_SZ) // 131072

typedef _Float16 half2v __attribute__((ext_vector_type(2)));
typedef _Float16 half4v __attribute__((ext_vector_type(4)));
typedef _Float16 half8v __attribute__((ext_vector_type(8)));
typedef float    f32x4  __attribute__((ext_vector_type(4)));

static __device__ __forceinline__ float fdot2f(uint a, uint b, float acc) {
#if __has_builtin(__builtin_amdgcn_fdot2)
  return __builtin_amdgcn_fdot2(__builtin_bit_cast(half2v, a),
                                __builtin_bit_cast(half2v, b), acc, false);
#else
  half2v av = __builtin_bit_cast(half2v, a), bv = __builtin_bit_cast(half2v, b);
  acc = fmaf((float)av[0], (float)bv[0], acc);
  acc = fmaf((float)av[1], (float)bv[1], acc);
  return acc;
#endif
}

static __device__ __forceinline__ float h2f(ushort u) {
  return (float)__builtin_bit_cast(_Float16, u);
}
static __device__ __forceinline__ ushort f2h(float x) {
  return __builtin_bit_cast(ushort, (_Float16)x);
}
static __device__ __forceinline__ float fast_rcp(float x) {
  return __builtin_amdgcn_rcpf(x);
}

// quad_perm DPP: xor1 = [1,0,3,2] = 0xB1, xor2 = [2,3,0,1] = 0x4E
#define QDPP(x, ctrl)                                                         \
  __builtin_bit_cast(float, __builtin_amdgcn_update_dpp(                      \
      0, __builtin_bit_cast(int, (x)), (ctrl), 0xF, 0xF, true))

// ---------- prep 1: Wx f32 -> f16 (GEMM B operand) ----------
__global__ void prep_wx(const float* __restrict__ Wx, ushort* __restrict__ Wxh) {
  int i = blockIdx.x * 256 + threadIdx.x;
  if (i < G3 * D_SZ) Wxh[i] = f2h(Wx[i]);
}

// ---------- prep 2: Wh -> per-thread packed f16-pair dwords for gru_rec ----------
// gru_rec: 1024 threads, quad q=g owns unit g. Lane j of quad holds, for each of
// the 3 gate rows {g, 256+g, 512+g}, the 32 h-pair-dwords kd = 32j + 4c + e
// (c=0..7, e=0..3). w[s], s = 32*row_sel + 4*c + e, loaded as 24 uint4 at
// dword ((s4*1024 + tid)*4 + e), s4 = s>>2.
__global__ void prep_wq(const float* __restrict__ Wh, uint* __restrict__ Wq) {
  int f = blockIdx.x * 256 + threadIdx.x; // flat dword 0..98303
  int e = f & 3;
  int tmp = f >> 2;        // s4*1024 + tid
  int tid = tmp & 1023;
  int s4 = tmp >> 10;      // 0..23
  int row_sel = s4 >> 3;   // 0..2
  int c = s4 & 7;          // 0..7
  int g = tid >> 2, j = tid & 3;
  int kd = 32 * j + 4 * c + e;
  int row = 256 * row_sel + g;
  float a = Wh[(size_t)row * D_SZ + 2 * kd];
  float b = Wh[(size_t)row * D_SZ + 2 * kd + 1];
  Wq[f] = (uint)f2h(a) | ((uint)f2h(b) << 16);
}

// ---------- GEMM: xs[m, g] = inputs[m, :] . Wx[g, :] + bx[g], stored f16 ----------
__global__ __launch_bounds__(256) void gemm_x(
    const float* __restrict__ A,   // [M_SZ, 256] f32
    const ushort* __restrict__ Bw, // Wx f16 [768, 256]
    const float* __restrict__ bx,  // [768] f32
    ushort* __restrict__ xs) {     // [M_SZ, 768] f16
  __shared__ _Float16 As[128][72];
  __shared__ _Float16 Bs[256][72];
  const int nt = blockIdx.x, mt = blockIdx.y;
  const int tid = threadIdx.x;
  const int lane = tid & 63, wv = tid >> 6;
  const int wr = (wv >> 1) * 64, wc = (wv & 1) * 128;
  const int l15 = lane & 15, l4 = lane >> 4;
  f32x4 acc[4][8] = {};
  for (int kt = 0; kt < 4; kt++) {
#pragma unroll
    for (int i = 0; i < 8; i++) {
      int f = tid + i * 256;
      int r = f >> 4, c4 = f & 15;
      float4 v = *(const float4*)(A + (size_t)(mt * 128 + r) * D_SZ + kt * 64 + c4 * 4);
      half4v h;
      h[0] = (_Float16)v.x; h[1] = (_Float16)v.y;
      h[2] = (_Float16)v.z; h[3] = (_Float16)v.w;
      *(half4v*)&As[r][c4 * 4] = h;
    }
#pragma unroll
    for (int i = 0; i < 8; i++) {
      int f = tid + i * 256;
      int r = f >> 3, c8 = f & 7;
      uint4 v = *(const uint4*)(Bw + (size_t)(nt * 256 + r) * D_SZ + kt * 64 + c8 * 8);
      *(uint4*)&Bs[r][c8 * 8] = v;
    }
    __syncthreads();
#pragma unroll
    for (int kk = 0; kk < 2; kk++) {
      half8v af[4], bf[8];
#pragma unroll
      for (int m = 0; m < 4; m++)
        af[m] = *(const half8v*)&As[wr + m * 16 + l15][kk * 32 + l4 * 8];
#pragma unroll
      for (int n = 0; n < 8; n++)
        bf[n] = *(const half8v*)&Bs[wc + n * 16 + l15][kk * 32 + l4 * 8];
#pragma unroll
      for (int m = 0; m < 4; m++) {
#pragma unroll
        for (int n = 0; n < 8; n++) {
          acc[m][n] = __builtin_amdgcn_mfma_f32_16x16x32_f16(af[m], bf[n], acc[m][n], 0, 0, 0);
        }
      }
    }
    __syncthreads();
  }
#pragma unroll
  for (int n = 0; n < 8; n++) {
    int col = nt * 256 + wc + n * 16 + l15;
    float bxv = bx[col];
#pragma unroll
    for (int m = 0; m < 4; m++) {
#pragma unroll
      for (int v4 = 0; v4 < 4; v4++) {
        int row = mt * 128 + wr + m * 16 + l4 * 4 + v4;
        xs[(size_t)row * G3 + col] = f2h(acc[m][n][v4] + bxv);
      }
    }
  }
}

// ---------- recurrence: 1024 threads (16 waves, 4 waves/SIMD, 128-VGPR cap) ----
// Quad g = tid>>2 owns hidden unit g; lane j = tid&3 holds 32 w-dwords per gate
// row (96 total). 8 ds_read_b128/step for the lane's h-slice; DPP quad
// butterfly combines partial dots; gate math redundant per quad; lane 0 writes.
// One barrier per step; h double-buffered in LDS.
__global__ __launch_bounds__(1024, 4) void gru_rec(
    const ushort* __restrict__ xs, // [B, T, 768] f16
    const uint* __restrict__ Wq,   // packed per-thread weights
    const float* __restrict__ bh,  // [768]
    const float* __restrict__ hid, // [1, B, 256]
    float* __restrict__ out) {     // [B, T, 256] f32
  const int b = blockIdx.x;
  const int tid = threadIdx.x;
  const int g = tid >> 2, j = tid & 3;

  __shared__ alignas(16) ushort hb[2][H_SZ];

  // 24 coalesced dwordx4 weight loads -> 96 registers
  uint w[96];
  {
    const uint4* wp = (const uint4*)Wq + tid;
#pragma unroll
    for (int s4 = 0; s4 < 24; s4++) {
      uint4 v = wp[(size_t)s4 * 1024];
      w[4 * s4 + 0] = v.x; w[4 * s4 + 1] = v.y;
      w[4 * s4 + 2] = v.z; w[4 * s4 + 3] = v.w;
    }
  }
  const float bhr = bh[g], bhu = bh[256 + g], bhn = bh[512 + g];
  float hprev = hid[b * H_SZ + g];
  if (j == 0) hb[0][g] = f2h(hprev);
  __syncthreads();

  const ushort* xrow = xs + (size_t)b * T_SZ * G3;
  float* orow = out + (size_t)b * T_SZ * H_SZ + g;
  const ushort* hsl = &hb[0][j * 64]; // lane's 128B h-slice (buffer 1 at +512B)

  // 2-step x prefetch ring
  ushort xr0 = xrow[g], xu0 = xrow[256 + g], xn0 = xrow[512 + g];
  ushort xr1 = xrow[G3 + g], xu1 = xrow[G3 + 256 + g], xn1 = xrow[G3 + 512 + g];

#define GRU_STEP(CUR, NXT, TOFF, XR, XU, XN)                                   \
  {                                                                            \
    float xrf = h2f(XR), xuf = h2f(XU), xnf = h2f(XN);                         \
    {                                                                          \
      int pfo = (TOFF) + 2;                                                    \
      if (pfo >= T_SZ) pfo = T_SZ - 1;                                         \
      const ushort* pf = xrow + (size_t)pfo * G3;                              \
      XR = pf[g]; XU = pf[256 + g]; XN = pf[512 + g];                          \
    }                                                                          \
    float aR = 0.f, aU = 0.f, aN = 0.f;                                        \
    const uint4* hq = (const uint4*)(hsl + (CUR) * H_SZ);                      \
    _Pragma("unroll")                                                          \
    for (int c = 0; c < 8; c++) {                                              \
      uint4 q = hq[c];                                                         \
      aR = fdot2f(w[4 * c + 0], q.x, aR);                                      \
      aU = fdot2f(w[32 + 4 * c + 0], q.x, aU);                                 \
      aN = fdot2f(w[64 + 4 * c + 0], q.x, aN);                                 \
      aR = fdot2f(w[4 * c + 1], q.y, aR);                                      \
      aU = fdot2f(w[32 + 4 * c + 1], q.y, aU);                                 \
      aN = fdot2f(w[64 + 4 * c + 1], q.y, aN);                                 \
      aR = fdot2f(w[4 * c + 2], q.z, aR);                                      \
      aU = fdot2f(w[32 + 4 * c + 2], q.z, aU);                                 \
      aN = fdot2f(w[64 + 4 * c + 2], q.z, aN);                                 \
      aR = fdot2f(w[4 * c + 3], q.w, aR);                                      \
      aU = fdot2f(w[32 + 4 * c + 3], q.w, aU);                                 \
      aN = fdot2f(w[64 + 4 * c + 3], q.w, aN);                                 \
    }                                                                          \
    aR += QDPP(aR, 0xB1); aR += QDPP(aR, 0x4E);                                \
    aU += QDPP(aU, 0xB1); aU += QDPP(aU, 0x4E);                                \
    aN += QDPP(aN, 0xB1); aN += QDPP(aN, 0x4E);                                \
    float r_ = fast_rcp(1.f + __expf(-(xrf + aR + bhr)));                      \
    float u_ = fast_rcp(1.f + __expf(-(xuf + aU + bhu)));                      \
    float arg = xnf + r_ * (aN + bhn);                                         \
    float e2 = __expf(-2.f * fabsf(arg));                                      \
    float th = copysignf((1.f - e2) * fast_rcp(1.f + e2), arg);                 \
    float hn = u_ * hprev + (1.f - u_) * th;                                    \
    if (j == 0) {                                                               \
      orow[(size_t)(TOFF) * H_SZ] = hn;                                         \
      hb[NXT][g] = f2h(hn);                                                     \
    }                                                                           \
    hprev = hn;                                                                 \
    asm volatile("s_waitcnt lgkmcnt(0)" ::: "memory");                          \
    __builtin_amdgcn_s_barrier();                                               \
  }

#pragma unroll 1
  for (int t = 0; t < T_SZ; t += 2) {
    GRU_STEP(0, 1, t, xr0, xu0, xn0)
    GRU_STEP(1, 0, t + 1, xr1, xu1, xn1)
  }
#undef GRU_STEP
}

extern "C" void kernel_launch(void* const* d_in, const int* in_sizes, int n_in,
                              void* d_out, int out_size, void* d_ws, size_t ws_size,
                              hipStream_t stream) {
  const float* inp = (const float*)d_in[0]; // [B,T,D] f32
  const float* hid = (const float*)d_in[1]; // [1,B,H] f32
  const float* Wx  = (const float*)d_in[2]; // [768,256] f32
  const float* bx  = (const float*)d_in[3]; // [768] f32
  const float* Wh  = (const float*)d_in[4]; // [768,256] f32
  const float* bh  = (const float*)d_in[5]; // [768] f32
  float* out = (float*)d_out;

  // workspace: xs f16 [M_SZ,768] (192 MiB), Wxh f16 (384 KiB), Wq uint (384 KiB)
  char* ws = (char*)d_ws;
  ushort* xs = (ushort*)ws;
  size_t xs_bytes = (size_t)M_SZ * G3 * sizeof(ushort);
  ushort* Wxh = (ushort*)(ws + xs_bytes);
  uint* Wq = (uint*)(ws + xs_bytes + (size_t)G3 * D_SZ * sizeof(ushort));

  prep_wx<<<768, 256, 0, stream>>>(Wx, Wxh);
  prep_wq<<<384, 256, 0, stream>>>(Wh, Wq);
  gemm_x<<<dim3(3, 1024), 256, 0, stream>>>(inp, Wxh, bx, xs);
  gru_rec<<<B_SZ, 1024, 0, stream>>>(xs, Wq, bh, hid, out);
}

// Round 6
// 2508.798 us; speedup vs baseline: 2.3529x; 1.0235x over previous
//
#include <hip/hip_runtime.h>
#include <hip/hip_fp16.h>

#define B_SZ 64
#define T_SZ 2048
#define D_SZ 256
#define H_SZ 256
#define G3   768
#define M_SZ (B_SZ * T_SZ) // 131072

typedef _Float16 half2v __attribute__((ext_vector_type(2)));
typedef _Float16 half4v __attribute__((ext_vector_type(4)));
typedef _Float16 half8v __attribute__((ext_vector_type(8)));
typedef float    f32x4  __attribute__((ext_vector_type(4)));

static __device__ __forceinline__ float fdot2f(uint a, uint b, float acc) {
#if __has_builtin(__builtin_amdgcn_fdot2)
  return __builtin_amdgcn_fdot2(__builtin_bit_cast(half2v, a),
                                __builtin_bit_cast(half2v, b), acc, false);
#else
  half2v av = __builtin_bit_cast(half2v, a), bv = __builtin_bit_cast(half2v, b);
  acc = fmaf((float)av[0], (float)bv[0], acc);
  acc = fmaf((float)av[1], (float)bv[1], acc);
  return acc;
#endif
}

static __device__ __forceinline__ float h2f(ushort u) {
  return (float)__builtin_bit_cast(_Float16, u);
}
static __device__ __forceinline__ ushort f2h(float x) {
  return __builtin_bit_cast(ushort, (_Float16)x);
}
static __device__ __forceinline__ float fast_rcp(float x) {
  return __builtin_amdgcn_rcpf(x);
}

// ---------- prep 1: Wx f32 -> f16 (GEMM B operand) ----------
__global__ void prep_wx(const float* __restrict__ Wx, ushort* __restrict__ Wxh) {
  int i = blockIdx.x * 256 + threadIdx.x;
  if (i < G3 * D_SZ) Wxh[i] = f2h(Wx[i]);
}

// ---------- prep 2: Wh -> packed f16-pair dwords, dwordx4-coalesced ----------
// gru_rec thread j (0..767) reads uint4 slot s4 (0..31) at (s4*768 + j).
// Slot s4's 4 dwords e=0..3 are h-pairs kp = 4*s4 + e of row j:
//   Wq[((s4*768 + j)*4 + e)] = pack(f16(Wh[j][2kp]), f16(Wh[j][2kp+1]))
__global__ void prep_wq(const float* __restrict__ Wh, uint* __restrict__ Wq) {
  int f = blockIdx.x * 256 + threadIdx.x; // 0 .. 98303
  int e = f & 3;
  int t2 = f >> 2;
  int j = t2 % G3;
  int s4 = t2 / G3;     // 0..31
  int kp = 4 * s4 + e;  // 0..127
  float a = Wh[(size_t)j * D_SZ + 2 * kp];
  float b = Wh[(size_t)j * D_SZ + 2 * kp + 1];
  Wq[f] = (uint)f2h(a) | ((uint)f2h(b) << 16);
}

// ---------- GEMM: xs[m, g] = inputs[m, :] . Wx[g, :] + bx[g], stored f16 ----------
__global__ __launch_bounds__(256) void gemm_x(
    const float* __restrict__ A,   // [M_SZ, 256] f32
    const ushort* __restrict__ Bw, // Wx f16 [768, 256]
    const float* __restrict__ bx,  // [768] f32
    ushort* __restrict__ xs) {     // [M_SZ, 768] f16
  __shared__ _Float16 As[128][72];
  __shared__ _Float16 Bs[256][72];
  const int nt = blockIdx.x, mt = blockIdx.y;
  const int tid = threadIdx.x;
  const int lane = tid & 63, wv = tid >> 6;
  const int wr = (wv >> 1) * 64, wc = (wv & 1) * 128;
  const int l15 = lane & 15, l4 = lane >> 4;
  f32x4 acc[4][8] = {};
  for (int kt = 0; kt < 4; kt++) {
#pragma unroll
    for (int i = 0; i < 8; i++) {
      int f = tid + i * 256;
      int r = f >> 4, c4 = f & 15;
      float4 v = *(const float4*)(A + (size_t)(mt * 128 + r) * D_SZ + kt * 64 + c4 * 4);
      half4v h;
      h[0] = (_Float16)v.x; h[1] = (_Float16)v.y;
      h[2] = (_Float16)v.z; h[3] = (_Float16)v.w;
      *(half4v*)&As[r][c4 * 4] = h;
    }
#pragma unroll
    for (int i = 0; i < 8; i++) {
      int f = tid + i * 256;
      int r = f >> 3, c8 = f & 7;
      uint4 v = *(const uint4*)(Bw + (size_t)(nt * 256 + r) * D_SZ + kt * 64 + c8 * 8);
      *(uint4*)&Bs[r][c8 * 8] = v;
    }
    __syncthreads();
#pragma unroll
    for (int kk = 0; kk < 2; kk++) {
      half8v af[4], bf[8];
#pragma unroll
      for (int m = 0; m < 4; m++)
        af[m] = *(const half8v*)&As[wr + m * 16 + l15][kk * 32 + l4 * 8];
#pragma unroll
      for (int n = 0; n < 8; n++)
        bf[n] = *(const half8v*)&Bs[wc + n * 16 + l15][kk * 32 + l4 * 8];
#pragma unroll
      for (int m = 0; m < 4; m++) {
#pragma unroll
        for (int n = 0; n < 8; n++) {
          acc[m][n] = __builtin_amdgcn_mfma_f32_16x16x32_f16(af[m], bf[n], acc[m][n], 0, 0, 0);
        }
      }
    }
    __syncthreads();
  }
#pragma unroll
  for (int n = 0; n < 8; n++) {
    int col = nt * 256 + wc + n * 16 + l15;
    float bxv = bx[col];
#pragma unroll
    for (int m = 0; m < 4; m++) {
#pragma unroll
      for (int v4 = 0; v4 < 4; v4++) {
        int row = mt * 128 + wr + m * 16 + l4 * 4 + v4;
        xs[(size_t)row * G3 + col] = f2h(acc[m][n][v4] + bxv);
      }
    }
  }
}

// ---------- recurrence: 768 threads (12 waves, 3 waves/SIMD, 170-reg budget) ----
// Thread j owns pre-activation row j (w[128] f16-pair dwords, VGPR-resident).
// h broadcast from LDS (uniform addresses -> conflict-free). 2 raw barriers/step
// with lgkmcnt-only waits (out-stores and x-loads stay in flight).
__global__ __launch_bounds__(768, 3) void gru_rec(
    const ushort* __restrict__ xs, // [B, T, 768] f16
    const uint* __restrict__ Wq,   // packed per-thread weights
    const float* __restrict__ bh,  // [768]
    const float* __restrict__ hid, // [1, B, 256]
    float* __restrict__ out) {     // [B, T, 256] f32
  const int b = blockIdx.x;
  const int j = threadIdx.x;
  __shared__ alignas(16) ushort h16[H_SZ];
  __shared__ float rs[H_SZ];
  __shared__ float us[H_SZ];

  // 32 coalesced dwordx4 weight loads -> 128 registers
  uint4 w4[32];
  {
    const uint4* wp = (const uint4*)Wq;
#pragma unroll
    for (int s4 = 0; s4 < 32; s4++) w4[s4] = wp[(size_t)s4 * G3 + j];
  }
  const float bhj = bh[j];
  if (j < H_SZ) h16[j] = f2h(hid[b * H_SZ + j]);
  __syncthreads();

  const ushort* xrow = xs + (size_t)b * T_SZ * G3 + j;
  float* orow = out + (size_t)b * T_SZ * H_SZ;
  ushort xu = xrow[0];

#pragma unroll 1
  for (int t = 0; t < T_SZ; t++) {
    // prefetch next step's x (latency hides under the dot chain)
    ushort xnext = (t + 1 < T_SZ) ? xrow[(size_t)(t + 1) * G3] : (ushort)0;
    float x = h2f(xu);

    // dot: Wh[j,:] . h  (128 dot2, 4 chains, h broadcast from LDS)
    float d0 = 0.f, d1 = 0.f, d2 = 0.f, d3 = 0.f;
    const uint4* hq = (const uint4*)h16;
#pragma unroll
    for (int c = 0; c < 32; c++) {
      uint4 q = hq[c];
      uint4 wv = w4[c];
      d0 = fdot2f(wv.x, q.x, d0);
      d1 = fdot2f(wv.y, q.y, d1);
      d2 = fdot2f(wv.z, q.z, d2);
      d3 = fdot2f(wv.w, q.w, d3);
    }
    float pre = ((d0 + d1) + (d2 + d3)) + bhj;

    if (j < 512) {
      float a = pre + x;                  // x_r + h_r  |  x_u + h_u
      float s = fast_rcp(1.f + __expf(-a));
      if (j < H_SZ) rs[j] = s;
      else          us[j - H_SZ] = s;
    }
    asm volatile("s_waitcnt lgkmcnt(0)" ::: "memory");
    __builtin_amdgcn_s_barrier();

    if (j >= 512) {                       // gate-n threads do the combine
      int i = j - 512;
      float r = rs[i], u = us[i];
      float hold = h2f(h16[i]);
      float arg = x + r * pre;            // x_n + reset*h_n
      float e = __expf(-2.f * fabsf(arg));
      float th = copysignf((1.f - e) * fast_rcp(1.f + e), arg);
      float hn = u * hold + (1.f - u) * th;
      orow[(size_t)t * H_SZ + i] = hn;    // fire-and-forget
      h16[i] = f2h(hn);
    }
    asm volatile("s_waitcnt lgkmcnt(0)" ::: "memory");
    __builtin_amdgcn_s_barrier();
    xu = xnext;
  }
}

extern "C" void kernel_launch(void* const* d_in, const int* in_sizes, int n_in,
                              void* d_out, int out_size, void* d_ws, size_t ws_size,
                              hipStream_t stream) {
  const float* inp = (const float*)d_in[0]; // [B,T,D] f32
  const float* hid = (const float*)d_in[1]; // [1,B,H] f32
  const float* Wx  = (const float*)d_in[2]; // [768,256] f32
  const float* bx  = (const float*)d_in[3]; // [768] f32
  const float* Wh  = (const float*)d_in[4]; // [768,256] f32
  const float* bh  = (const float*)d_in[5]; // [768] f32
  float* out = (float*)d_out;

  // workspace: xs f16 [M_SZ,768] (192 MiB), Wxh f16 (384 KiB), Wq uint (384 KiB)
  char* ws = (char*)d_ws;
  ushort* xs = (ushort*)ws;
  size_t xs_bytes = (size_t)M_SZ * G3 * sizeof(ushort);
  ushort* Wxh = (ushort*)(ws + xs_bytes);
  uint* Wq = (uint*)(ws + xs_bytes + (size_t)G3 * D_SZ * sizeof(ushort));

  prep_wx<<<768, 256, 0, stream>>>(Wx, Wxh);
  prep_wq<<<384, 256, 0, stream>>>(Wh, Wq);
  gemm_x<<<dim3(3, 1024), 256, 0, stream>>>(inp, Wxh, bx, xs);
  gru_rec<<<B_SZ, G3, 0, stream>>>(xs, Wq, bh, hid, out);
}